// Round 21
// baseline (599.116 us; speedup 1.0000x reference)
//
#include <hip/hip_runtime.h>

#define BATCH 16384
#define KDIM  8192
#define ODIM  32
#define SK    8
#define KSLICE (KDIM / SK)       // 1024 k per block
#define KHALF  (KSLICE / 2)      // 512 k per wave
#define KT    32                 // k per wave-tile (128 B per row bursts)
#define NT    (KHALF / KT)       // 16 tiles
#define THREADS 256

typedef short bf16x8 __attribute__((ext_vector_type(8)));
typedef float f32x16 __attribute__((ext_vector_type(16)));

__device__ __forceinline__ uint2 pack_bf16rn(float4 v) {
    unsigned b0 = __float_as_uint(v.x), b1 = __float_as_uint(v.y);
    unsigned b2 = __float_as_uint(v.z), b3 = __float_as_uint(v.w);
    uint2 r;
    r.x = ((b0 + 0x8000u) >> 16) | ((b1 + 0x8000u) & 0xFFFF0000u);
    r.y = ((b2 + 0x8000u) >> 16) | ((b3 + 0x8000u) & 0xFFFF0000u);
    return r;
}

// ---------------------------------------------------------------------------
// Prep: bwTo[o][k] = sign(w[o][k]) as bf16 (+-1.0 exact / 0), + |w| partials
// ---------------------------------------------------------------------------
__global__ void prep_kernel(const float* __restrict__ w,
                            unsigned short* __restrict__ bwTo,
                            float* __restrict__ partial) {
    int idx = blockIdx.x * 256 + threadIdx.x;     // = o*8192 + k, coalesced
    float v = w[idx];
    bwTo[idx] = (v > 0.f) ? 0x3F80u : ((v < 0.f) ? 0xBF80u : 0u);

    float a = fabsf(v);
    #pragma unroll
    for (int off = 32; off; off >>= 1) a += __shfl_down(a, off, 64);
    __shared__ float red[4];
    int lane = threadIdx.x & 63, wv = threadIdx.x >> 6;
    if (lane == 0) red[wv] = a;
    __syncthreads();
    if (threadIdx.x == 0)
        partial[blockIdx.x] = (red[0] + red[1]) + (red[2] + red[3]);
}

// ---------------------------------------------------------------------------
// Main: R20's zero-barrier wave-private MFMA pipeline at 32 waves/CU, plus
// fused split-K finalization (last-block pattern): after the coalesced
// partial write, each block does threadfence + device-scope atomicAdd on
// cnt[rb]; the 8th block fences, recomputes scale from the |w| partials
// (same tree -> bit-identical), sums the 8 pout slices in FIXED index order
// (deterministic regardless of arrival order), scales, writes out.
// Removes the reduce kernel launch + full inter-kernel drain.
// ---------------------------------------------------------------------------
__global__ __launch_bounds__(THREADS, 8)
void main_kernel(const float* __restrict__ x,
                 const unsigned short* __restrict__ bwTo,
                 const float* __restrict__ partial,
                 float* __restrict__ pout,
                 unsigned* __restrict__ cnt,
                 float* __restrict__ out) {
    __shared__ union {
        unsigned short buf[4][2][32][KT];  // [wave][db][row][32 bf16] = 16 KB
        float part[2][64][33];             // 16.9 KB k-half combine
    } sm;
    __shared__ unsigned done;
    __shared__ float red[4];
    __shared__ float sbc;

    const int tid  = threadIdx.x;
    const int wv   = __builtin_amdgcn_readfirstlane(tid >> 6);
    const int lane = tid & 63;
    const int l31  = lane & 31, lhi = lane >> 5;
    const int kH   = wv & 1;           // k half (512 k)
    const int rH   = wv >> 1;          // row half (32 rows)
    const int kb   = blockIdx.x & 7;   // XCD-locked weight slice
    const int rb   = blockIdx.x >> 3;  // 0..255
    const size_t rowbase = (size_t)rb * 64;
    const int kbase = kb * KSLICE + kH * KHALF;

    // staging: load j covers rows rH*32 + 8j + srow8; sc = 16B fp32 chunk
    const int srow8 = lane >> 3;               // 0..7
    const int sc    = lane & 7;                // 0..7 (128 B per row)
    const float* __restrict__ g0 =
        x + (rowbase + rH * 32 + srow8) * (size_t)KDIM + kbase + 4 * sc;
    const float* __restrict__ g1 = g0 + (size_t)8  * KDIM;
    const float* __restrict__ g2 = g0 + (size_t)16 * KDIM;
    const float* __restrict__ g3 = g0 + (size_t)24 * KDIM;

    // LDS write offset (ushort units): slot independent of j (8j>>1 ≡ 0 mod 4)
    const int wslot = (2 * ((sc >> 1) ^ ((srow8 >> 1) & 3)) + (sc & 1)) * 4;

    // B: 8 consecutive bf16 of weight row o=l31 (L2-resident 64KB slice)
    const unsigned short* __restrict__ bp =
        bwTo + (size_t)l31 * KDIM + kbase + lhi * 8;

    // A-read offsets (ushort units): row l31, step s: pair (2s|lhi)^pr
    const int pr  = (l31 >> 1) & 3;
    const int ro0 = l31 * KT + ((lhi    ) ^ pr) * 8;
    const int ro1 = l31 * KT + ((2 | lhi) ^ pr) * 8;
    const unsigned short* const rbA = &sm.buf[wv][0][0][0];
    const unsigned short* const rbB = &sm.buf[wv][1][0][0];

    f32x16 acc;
    #pragma unroll
    for (int i = 0; i < 16; ++i) acc[i] = 0.f;

    uint2 pk0, pk1, pk2, pk3;

#define LOADPACK(t) do {                                                      \
        float4 s0 = *(const float4*)(g0 + (t) * KT);                          \
        float4 s1 = *(const float4*)(g1 + (t) * KT);                          \
        float4 s2 = *(const float4*)(g2 + (t) * KT);                          \
        float4 s3 = *(const float4*)(g3 + (t) * KT);                          \
        pk0 = pack_bf16rn(s0); pk1 = pack_bf16rn(s1);                         \
        pk2 = pack_bf16rn(s2); pk3 = pack_bf16rn(s3);                         \
    } while (0)

#define WRITET(db) do {                                                       \
        *(uint2*)&sm.buf[wv][db][ 0 + srow8][wslot] = pk0;                    \
        *(uint2*)&sm.buf[wv][db][ 8 + srow8][wslot] = pk1;                    \
        *(uint2*)&sm.buf[wv][db][16 + srow8][wslot] = pk2;                    \
        *(uint2*)&sm.buf[wv][db][24 + srow8][wslot] = pk3;                    \
    } while (0)

#define STEP(base, ro, boff) do {                                             \
        bf16x8 av = *(const bf16x8*)((base) + (ro));                          \
        bf16x8 bv = *(const bf16x8*)(bp + (boff));                            \
        acc = __builtin_amdgcn_mfma_f32_32x32x16_bf16(av, bv, acc, 0, 0, 0);  \
    } while (0)

    // prologue: tile 0 staged; tile 1 packed in regs
    LOADPACK(0);
    WRITET(0);
    LOADPACK(1);

    for (int t = 0; t < NT; ++t) {
        const unsigned short* base = (t & 1) ? rbB : rbA;
        STEP(base, ro0, t * KT);           // k-step 0 (K=16)
        STEP(base, ro1, t * KT + 16);      // k-step 1
        if (t + 1 < NT) WRITET((t + 1) & 1);   // stage tile t+1 (pk -> LDS)
        if (t + 2 < NT) LOADPACK(t + 2);       // refill pk (regs free post-write)
    }
#undef LOADPACK
#undef WRITET
#undef STEP

    // combine k-halves via LDS, coalesced partial write
    __syncthreads();
    #pragma unroll
    for (int r = 0; r < 16; ++r) {
        int row32 = (r & 3) + 8 * (r >> 2) + 4 * lhi;   // C/D layout (m74/m101)
        sm.part[kH][rH * 32 + row32][l31] = acc[r];
    }
    __syncthreads();

    float* __restrict__ pb = pout + ((size_t)kb * BATCH + rowbase) * ODIM;
    #pragma unroll
    for (int i = 0; i < 8; ++i) {
        int j = tid + THREADS * i;        // j = r*32 + o, coalesced
        int r = j >> 5, o = j & 31;
        pb[j] = sm.part[0][r][o] + sm.part[1][r][o];
    }

    // ---- fused split-K finalization (last-block-per-rb, deterministic) ----
    __threadfence();                       // release: partial slice visible
    if (tid == 0) done = atomicAdd(&cnt[rb], 1u);
    __syncthreads();                       // 'done' valid block-wide
    if (done == 7u) {                      // uniform branch: this is the 8th
        __threadfence();                   // acquire: other slices visible
        // scale = mean|w| from the 1024 prep partials (same tree as before)
        float a = (partial[tid] + partial[tid + 256]) +
                  (partial[tid + 512] + partial[tid + 768]);
        #pragma unroll
        for (int off = 32; off; off >>= 1) a += __shfl_down(a, off, 64);
        if ((tid & 63) == 0) red[tid >> 6] = a;
        __syncthreads();
        if (tid == 0)
            sbc = ((red[0] + red[1]) + (red[2] + red[3])) / (float)(ODIM * KDIM);
        __syncthreads();
        const float s = sbc;

        const float* __restrict__ p0 = pout + rowbase * ODIM;
        float* __restrict__ ob = out + rowbase * ODIM;
        const int STRIDE = BATCH * ODIM;
        #pragma unroll
        for (int i = 0; i < 8; ++i) {
            int j = tid + THREADS * i;     // coalesced within each slice
            float v = 0.f;
            #pragma unroll
            for (int kk = 0; kk < SK; ++kk)   // FIXED order -> deterministic
                v += p0[j + kk * STRIDE];
            ob[j] = v * s;
        }
    }
}

// ---------------------------------------------------------------------------
extern "C" void kernel_launch(void* const* d_in, const int* in_sizes, int n_in,
                              void* d_out, int out_size, void* d_ws, size_t ws_size,
                              hipStream_t stream) {
    const float* x = (const float*)d_in[0];
    const float* w = (const float*)d_in[1];
    float* out = (float*)d_out;

    float* wsf = (float*)d_ws;
    float* partial       = wsf;                            // 1024 floats
    unsigned short* bwTo = (unsigned short*)(wsf + 1024);  // 512 KB
    float* pout          = wsf + 1024 + (ODIM * KDIM / 2); // SK*2MB = 16 MB
    unsigned* cnt        = (unsigned*)(pout + (size_t)SK * BATCH * ODIM); // 256 u32

    hipMemsetAsync(cnt, 0, 256 * sizeof(unsigned), stream);  // graph-capturable
    prep_kernel<<<1024, 256, 0, stream>>>(w, bwTo, partial);
    main_kernel<<<256 * SK, THREADS, 0, stream>>>(x, bwTo, partial, pout, cnt, out);
}

// Round 22
// 120.247 us; speedup vs baseline: 4.9824x; 4.9824x over previous
//
#include <hip/hip_runtime.h>

#define BATCH 16384
#define KDIM  8192
#define ODIM  32
#define SK    8
#define KSLICE (KDIM / SK)       // 1024 k per block
#define KHALF  (KSLICE / 2)      // 512 k per wave
#define KT    32                 // k per wave-tile (128 B per row bursts)
#define NT    (KHALF / KT)       // 16 tiles
#define THREADS 256

typedef short bf16x8 __attribute__((ext_vector_type(8)));
typedef float f32x16 __attribute__((ext_vector_type(16)));

__device__ __forceinline__ uint2 pack_bf16rn(float4 v) {
    unsigned b0 = __float_as_uint(v.x), b1 = __float_as_uint(v.y);
    unsigned b2 = __float_as_uint(v.z), b3 = __float_as_uint(v.w);
    uint2 r;
    r.x = ((b0 + 0x8000u) >> 16) | ((b1 + 0x8000u) & 0xFFFF0000u);
    r.y = ((b2 + 0x8000u) >> 16) | ((b3 + 0x8000u) & 0xFFFF0000u);
    return r;
}

// ---------------------------------------------------------------------------
// Prep: bwTo[o][k] = sign(w[o][k]) as bf16 (+-1.0 exact / 0), + |w| partials
// ---------------------------------------------------------------------------
__global__ void prep_kernel(const float* __restrict__ w,
                            unsigned short* __restrict__ bwTo,
                            float* __restrict__ partial) {
    int idx = blockIdx.x * 256 + threadIdx.x;     // = o*8192 + k, coalesced
    float v = w[idx];
    bwTo[idx] = (v > 0.f) ? 0x3F80u : ((v < 0.f) ? 0xBF80u : 0u);

    float a = fabsf(v);
    #pragma unroll
    for (int off = 32; off; off >>= 1) a += __shfl_down(a, off, 64);
    __shared__ float red[4];
    int lane = threadIdx.x & 63, wv = threadIdx.x >> 6;
    if (lane == 0) red[wv] = a;
    __syncthreads();
    if (threadIdx.x == 0)
        partial[blockIdx.x] = (red[0] + red[1]) + (red[2] + red[3]);
}

// ---------------------------------------------------------------------------
// Main (R20, proven 120.4 us): zero-barrier wave-private MFMA pipeline at
// 32 waves/CU. KT=32 + bf16 LDS staging -> 16.4 KB/block -> 8 blocks/CU.
// Staging: 4 loads x (8 rows x 128 B), pack RTN bf16, ds_write_b64 swizzled
// slot = 2*((sc>>1)^((srow8>>1)&3)) + (sc&1); read pair g^((l31>>1)&3)
// undoes it (write 4 dwords/bank, read 8/bank = structural floors). All
// deps compiler-visible; no counted vmcnt, no block barriers in K-loop.
// NO __threadfence anywhere (R21 lesson: device-scope fence = per-XCD L2
// writeback storm, 5x regression). kb = bid&7 XCD-locked weights (L2-hot).
// Split-K=8 partials, separate reduce kernel, deterministic, no atomics.
// ---------------------------------------------------------------------------
__global__ __launch_bounds__(THREADS, 8)
void main_kernel(const float* __restrict__ x,
                 const unsigned short* __restrict__ bwTo,
                 float* __restrict__ pout) {
    __shared__ union {
        unsigned short buf[4][2][32][KT];  // [wave][db][row][32 bf16] = 16 KB
        float part[2][64][33];             // 16.9 KB k-half combine
    } sm;

    const int tid  = threadIdx.x;
    const int wv   = __builtin_amdgcn_readfirstlane(tid >> 6);
    const int lane = tid & 63;
    const int l31  = lane & 31, lhi = lane >> 5;
    const int kH   = wv & 1;           // k half (512 k)
    const int rH   = wv >> 1;          // row half (32 rows)
    const int kb   = blockIdx.x & 7;   // XCD-locked weight slice
    const int rb   = blockIdx.x >> 3;  // 0..255
    const size_t rowbase = (size_t)rb * 64;
    const int kbase = kb * KSLICE + kH * KHALF;

    // staging: load j covers rows rH*32 + 8j + srow8; sc = 16B fp32 chunk
    const int srow8 = lane >> 3;               // 0..7
    const int sc    = lane & 7;                // 0..7 (128 B per row)
    const float* __restrict__ g0 =
        x + (rowbase + rH * 32 + srow8) * (size_t)KDIM + kbase + 4 * sc;
    const float* __restrict__ g1 = g0 + (size_t)8  * KDIM;
    const float* __restrict__ g2 = g0 + (size_t)16 * KDIM;
    const float* __restrict__ g3 = g0 + (size_t)24 * KDIM;

    // LDS write offset (ushort units): slot independent of j (8j>>1 ≡ 0 mod 4)
    const int wslot = (2 * ((sc >> 1) ^ ((srow8 >> 1) & 3)) + (sc & 1)) * 4;

    // B: 8 consecutive bf16 of weight row o=l31 (L2-resident 64KB slice)
    const unsigned short* __restrict__ bp =
        bwTo + (size_t)l31 * KDIM + kbase + lhi * 8;

    // A-read offsets (ushort units): row l31, step s: pair (2s|lhi)^pr
    const int pr  = (l31 >> 1) & 3;
    const int ro0 = l31 * KT + ((lhi    ) ^ pr) * 8;
    const int ro1 = l31 * KT + ((2 | lhi) ^ pr) * 8;
    const unsigned short* const rbA = &sm.buf[wv][0][0][0];
    const unsigned short* const rbB = &sm.buf[wv][1][0][0];

    f32x16 acc;
    #pragma unroll
    for (int i = 0; i < 16; ++i) acc[i] = 0.f;

    uint2 pk0, pk1, pk2, pk3;

#define LOADPACK(t) do {                                                      \
        float4 s0 = *(const float4*)(g0 + (t) * KT);                          \
        float4 s1 = *(const float4*)(g1 + (t) * KT);                          \
        float4 s2 = *(const float4*)(g2 + (t) * KT);                          \
        float4 s3 = *(const float4*)(g3 + (t) * KT);                          \
        pk0 = pack_bf16rn(s0); pk1 = pack_bf16rn(s1);                         \
        pk2 = pack_bf16rn(s2); pk3 = pack_bf16rn(s3);                         \
    } while (0)

#define WRITET(db) do {                                                       \
        *(uint2*)&sm.buf[wv][db][ 0 + srow8][wslot] = pk0;                    \
        *(uint2*)&sm.buf[wv][db][ 8 + srow8][wslot] = pk1;                    \
        *(uint2*)&sm.buf[wv][db][16 + srow8][wslot] = pk2;                    \
        *(uint2*)&sm.buf[wv][db][24 + srow8][wslot] = pk3;                    \
    } while (0)

#define STEP(base, ro, boff) do {                                             \
        bf16x8 av = *(const bf16x8*)((base) + (ro));                          \
        bf16x8 bv = *(const bf16x8*)(bp + (boff));                            \
        acc = __builtin_amdgcn_mfma_f32_32x32x16_bf16(av, bv, acc, 0, 0, 0);  \
    } while (0)

    // prologue: tile 0 staged; tile 1 packed in regs
    LOADPACK(0);
    WRITET(0);
    LOADPACK(1);

    for (int t = 0; t < NT; ++t) {
        const unsigned short* base = (t & 1) ? rbB : rbA;
        STEP(base, ro0, t * KT);           // k-step 0 (K=16)
        STEP(base, ro1, t * KT + 16);      // k-step 1
        if (t + 1 < NT) WRITET((t + 1) & 1);   // stage tile t+1 (pk -> LDS)
        if (t + 2 < NT) LOADPACK(t + 2);       // refill pk (regs free post-write)
    }
#undef LOADPACK
#undef WRITET
#undef STEP

    // combine k-halves via LDS (only barriers in the kernel)
    __syncthreads();
    #pragma unroll
    for (int r = 0; r < 16; ++r) {
        int row32 = (r & 3) + 8 * (r >> 2) + 4 * lhi;   // C/D layout (m74/m101)
        sm.part[kH][rH * 32 + row32][l31] = acc[r];
    }
    __syncthreads();

    float* __restrict__ pb = pout + ((size_t)kb * BATCH + rowbase) * ODIM;
    #pragma unroll
    for (int i = 0; i < 8; ++i) {
        int j = tid + THREADS * i;        // j = r*32 + o, coalesced
        int r = j >> 5, o = j & 31;
        pb[j] = sm.part[0][r][o] + sm.part[1][r][o];
    }
}

// ---------------------------------------------------------------------------
// Final: recompute scale from |w| partials (deterministic), sum SK partials
// ---------------------------------------------------------------------------
__global__ void reduce_kernel(const float* __restrict__ pout,
                              const float* __restrict__ partial,
                              float* __restrict__ out) {
    const int t = threadIdx.x;
    float a = (partial[t] + partial[t + 256]) + (partial[t + 512] + partial[t + 768]);
    #pragma unroll
    for (int off = 32; off; off >>= 1) a += __shfl_down(a, off, 64);
    __shared__ float red[4];
    __shared__ float sbc;
    if ((t & 63) == 0) red[t >> 6] = a;
    __syncthreads();
    if (t == 0)
        sbc = ((red[0] + red[1]) + (red[2] + red[3])) / (float)(ODIM * KDIM);
    __syncthreads();
    const float s = sbc;

    const int STRIDE = BATCH * ODIM / 4;
    int i = blockIdx.x * 256 + t;
    const float4* p = (const float4*)pout;
    float4 r = p[i];
    #pragma unroll
    for (int k = 1; k < SK; ++k) {
        float4 A = p[i + k * STRIDE];
        r.x += A.x; r.y += A.y; r.z += A.z; r.w += A.w;
    }
    r.x *= s; r.y *= s; r.z *= s; r.w *= s;
    ((float4*)out)[i] = r;
}

// ---------------------------------------------------------------------------
extern "C" void kernel_launch(void* const* d_in, const int* in_sizes, int n_in,
                              void* d_out, int out_size, void* d_ws, size_t ws_size,
                              hipStream_t stream) {
    const float* x = (const float*)d_in[0];
    const float* w = (const float*)d_in[1];
    float* out = (float*)d_out;

    float* wsf = (float*)d_ws;
    float* partial       = wsf;                            // 1024 floats
    unsigned short* bwTo = (unsigned short*)(wsf + 1024);  // 512 KB
    float* pout          = wsf + 1024 + (ODIM * KDIM / 2); // SK*2MB = 16 MB

    prep_kernel<<<1024, 256, 0, stream>>>(w, bwTo, partial);
    main_kernel<<<256 * SK, THREADS, 0, stream>>>(x, bwTo, pout);
    reduce_kernel<<<BATCH * ODIM / 4 / 256, 256, 0, stream>>>(pout, partial, out);
}